// Round 6
// baseline (5495.809 us; speedup 1.0000x reference)
//
#include <hip/hip_runtime.h>
#include <stdint.h>

// LSTM: B=64, T=512, I=H=1024. bf16 MFMA path.
// Phase 1: Xg = x @ Wih^T + b  (m97-style 128x128 tile GEMM, permuted col layout)
// Phase 2: persistent 256-block kernel, 512 steps.
// R1: barrier rework — relaxed polling, Xg register prefetch.
// R2: zero cache-maintenance loop: h via agent-scope relaxed atomics.
// R3 (regressed): dataflow mask-loop — VALU-bound polling, MFMA serialization.
// R4: per-producer flags + 16-lane gather + __all ballot. 1724 us.
// R5 (regressed): tagged-h — poll mass scaled with data size, LLC congestion.
// R6 (regressed): 32-col blocks — doubled serial compute, stragglers weren't it.
// R7: BARRIER-FREE WAVE-AUTONOMOUS STEP. Each wave computes 4 gates x 4 hcols
//     (one interleaved 16-col MFMA tile) with FULL K=1024 -> no cross-wave
//     reduce, no __syncthreads in the loop. Gate->cell regroup via wave-local
//     LDS transpose (lgkmcnt only). Producer signal: per-wave store-drain +
//     LDS atomic counter; 4th wave publishes block flag. Poll unchanged
//     (1 gather + 1 ballot, now over all 64 producer blocks = the full-K
//     dependence R4 hid behind its barrier). Depth-2 ping-pong WAR-safe:
//     own poll (all flags >= t) certifies all readers of h(t-1) are done.

typedef __bf16 bf16x8 __attribute__((ext_vector_type(8)));
typedef float f32x4 __attribute__((ext_vector_type(4)));

#define BATCH 64
#define TSEQ 512
#define HID 1024
#define MROWS (BATCH * TSEQ)  // 32768
#define NGATE 4096

__device__ __forceinline__ unsigned short f2bf(float f) {
  union { float f; unsigned u; } v; v.f = f;
  unsigned r = (v.u + 0x7FFFu + ((v.u >> 16) & 1u)) >> 16;
  return (unsigned short)r;
}
__device__ __forceinline__ float bf2f(unsigned short u) {
  union { unsigned u; float f; } v; v.u = ((unsigned)u) << 16;
  return v.f;
}

__global__ void cvt_kernel(const float* __restrict__ src,
                           unsigned short* __restrict__ dst, int n4) {
  int i = blockIdx.x * blockDim.x + threadIdx.x;
  const int stride = gridDim.x * blockDim.x;
  for (; i < n4; i += stride) {
    float4 f = ((const float4*)src)[i];
    ushort4 u;
    u.x = f2bf(f.x); u.y = f2bf(f.y); u.z = f2bf(f.z); u.w = f2bf(f.w);
    ((ushort4*)dst)[i] = u;
  }
}

__device__ __forceinline__ void gl_lds16(const unsigned short* g, unsigned short* lds) {
  __builtin_amdgcn_global_load_lds(
      (const __attribute__((address_space(1))) unsigned int*)g,
      (__attribute__((address_space(3))) unsigned int*)lds, 16, 0, 0);
}

// ---------------- Phase 1 GEMM: Xg[r][perm(n)] = sum_k x[r][k]*Wih[n][k] + b[n]
// perm(n) = ((n&1023)>>4)*64 + (n>>10)*16 + (n&15).
__global__ __launch_bounds__(256, 2) void gemm_xg(
    const unsigned short* __restrict__ A,   // x_bf   [32768][1024]
    const unsigned short* __restrict__ B,   // Wih_bf [4096][1024]
    const float* __restrict__ bias,         // [4096]
    unsigned short* __restrict__ Xg)        // [32768][4096] permuted cols
{
  __shared__ __align__(16) unsigned short Asm[128 * 32];  // 8 KB, swizzled
  __shared__ __align__(16) unsigned short Bsm[128 * 32];
  const int tid = threadIdx.x;
  const int lane = tid & 63;
  const int wave = tid >> 6;
  const int row0 = blockIdx.y * 128;
  const int col0 = blockIdx.x * 128;
  const int wm = (wave >> 1) * 64;
  const int wn = (wave & 1) * 64;
  const int s_ml = lane >> 2;
  const int s_q = ((lane & 3) ^ (s_ml >> 1)) & 3;
  const int fm = lane & 15;
  const int fq = lane >> 4;
  const int swz = ((fq ^ (fm >> 1)) & 3) * 8;

  f32x4 acc[4][4] = {};

  for (int kt = 0; kt < 32; ++kt) {
    const int k0 = kt * 32;
    __syncthreads();
#pragma unroll
    for (int gI = 0; gI < 2; ++gI) {
      const int grp = wave * 2 + gI;
      const unsigned short* ga =
          A + (size_t)(row0 + grp * 16 + s_ml) * 1024 + k0 + s_q * 8;
      gl_lds16(ga, &Asm[grp * 512]);
      const unsigned short* gb =
          B + (size_t)(col0 + grp * 16 + s_ml) * 1024 + k0 + s_q * 8;
      gl_lds16(gb, &Bsm[grp * 512]);
    }
    __syncthreads();
    bf16x8 af[4], bfv[4];
#pragma unroll
    for (int mt = 0; mt < 4; ++mt) {
      const int m = wm + mt * 16 + fm;
      af[mt] = *(const bf16x8*)&Asm[(m >> 4) * 512 + fm * 32 + swz];
    }
#pragma unroll
    for (int nt = 0; nt < 4; ++nt) {
      const int n = wn + nt * 16 + fm;
      bfv[nt] = *(const bf16x8*)&Bsm[(n >> 4) * 512 + fm * 32 + swz];
    }
#pragma unroll
    for (int mt = 0; mt < 4; ++mt)
#pragma unroll
      for (int nt = 0; nt < 4; ++nt)
        acc[mt][nt] = __builtin_amdgcn_mfma_f32_16x16x32_bf16(
            af[mt], bfv[nt], acc[mt][nt], 0, 0, 0);
  }
#pragma unroll
  for (int nt = 0; nt < 4; ++nt) {
    const int nb = col0 + wn + nt * 16;
    const int pbase = ((nb & 1023) >> 4) * 64 + (nb >> 10) * 16;
    const float bv = bias[nb + fm];
#pragma unroll
    for (int mt = 0; mt < 4; ++mt) {
#pragma unroll
      for (int r = 0; r < 4; ++r) {
        const int row = row0 + wm + mt * 16 + fq * 4 + r;
        Xg[(size_t)row * 4096 + pbase + fm] = f2bf(acc[mt][nt][r] + bv);
      }
    }
  }
}

// Device-coherent 16B h-fragment load: two 8B agent-scope relaxed atomic loads.
__device__ __forceinline__ bf16x8 load_h16B(const unsigned short* p) {
  union { unsigned long long q[2]; bf16x8 v; } u;
  const unsigned long long* q = (const unsigned long long*)p;
  u.q[0] = __hip_atomic_load(q, __ATOMIC_RELAXED, __HIP_MEMORY_SCOPE_AGENT);
  u.q[1] = __hip_atomic_load(q + 1, __ATOMIC_RELAXED, __HIP_MEMORY_SCOPE_AGENT);
  return u.v;
}

// ---------------- Phase 2: persistent recurrence, barrier-free.
// 256 blocks: bn = blockIdx>>2 (hidden slice of 16), mi = blockIdx&3 (16 rows).
// Wave w computes hcols bn*16+w*4 .. +4, all 4 gates, FULL K=1024:
// MFMA tile cols ct = g*4+u  <-> Whh row n = g*1024 + bn*16 + w*4 + u.
// flag[mi][bn] = t+1 published by the block's 4th-draining wave (LDS counter).
__global__ __launch_bounds__(256, 1) void lstm_seq(
    const unsigned short* __restrict__ Whh,  // [4096][1024] bf16
    const unsigned short* __restrict__ Xg,   // [32768][4096] bf16 permuted
    float* __restrict__ out,
    unsigned short* __restrict__ hbuf,       // 2 x [64][1024] bf16 ping-pong
    unsigned int* __restrict__ flags)        // [4 groups][64 blocks] x 128B lines
{
  __shared__ float xpose[4][16][20];  // [wave][row][16 cols + 4 pad]
  __shared__ unsigned cnt;            // per-block wave-completion counter
  const int tid = threadIdx.x;
  const int lane = tid & 63;
  const int wave = tid >> 6;
  const int bn = blockIdx.x >> 2;
  const int mi = blockIdx.x & 3;
  const int fm = lane & 15;
  const int fq = lane >> 4;
  unsigned int* flg = flags + mi * 64 * 32;   // 32 uints = 128B per flag
  unsigned int* myflag = flg + bn * 32;
  unsigned int* pollp = flg + lane * 32;      // all 64 producer blocks

  if (tid == 0) cnt = 0;
  __syncthreads();  // one-time (counter init)

  // bfrag[ki]: B-frag col ct=fm -> gate g=fm>>2, u=fm&3.
  // n = g*1024 + bn*16 + wave*4 + u ; k = ki*32 + fq*8 .. +8
  bf16x8 bfrag[32];
  {
    const int g = fm >> 2, u = fm & 3;
    const unsigned short* wrow =
        Whh + (size_t)(g * 1024 + bn * 16 + wave * 4 + u) * 1024 + fq * 8;
#pragma unroll
    for (int ki = 0; ki < 32; ++ki) bfrag[ki] = *(const bf16x8*)(wrow + ki * 32);
  }

  // Elementwise mapping: row_e = lane>>2 (batch-local), u_e = lane&3 (hcol
  // within the wave's 4). One cell per lane.
  const int row_e = lane >> 2, u_e = lane & 3;
  const int gb = mi * 16 + row_e;                 // global batch row
  const int gj = bn * 16 + wave * 4 + u_e;        // global hidden index
  float c_reg = 0.f;

  unsigned short* h0 = hbuf;
  unsigned short* h1 = hbuf + BATCH * HID;

  // Xg permuted col for (gate g, hcol gj): bn*64 + g*16 + wave*4 + u_e
  const unsigned short* xrow =
      Xg + (size_t)gb * TSEQ * 4096 + bn * 64 + wave * 4 + u_e;
  float xpre[4];
#pragma unroll
  for (int g = 0; g < 4; ++g) xpre[g] = bf2f(xrow[g * 16]);

  for (int t = 0; t < TSEQ; ++t) {
    const unsigned short* hp = (t & 1) ? h1 : h0;
    unsigned short* hn = (t & 1) ? h0 : h1;
    const unsigned short* ab = hp + (size_t)(mi * 16 + fm) * 1024 + fq * 8;

    // Rotate Xg regs; issue prefetch for t+1 early (hides under the poll)
    float xcur[4];
#pragma unroll
    for (int g = 0; g < 4; ++g) xcur[g] = xpre[g];
    if (t < TSEQ - 1) {
      const unsigned short* xn = xrow + (size_t)(t + 1) * 4096;
#pragma unroll
      for (int g = 0; g < 4; ++g) xpre[g] = bf2f(xn[g * 16]);
    }

    // Wait for all 64 producer blocks (full-K dependence): 1 gather + 1 ballot
    // per pass. t=0: flags start at 0, no wait.
    if (t > 0) {
      for (;;) {
        const unsigned f = __hip_atomic_load(pollp, __ATOMIC_RELAXED,
                                             __HIP_MEMORY_SCOPE_AGENT);
        if (__all((int)(f >= (unsigned)t))) break;
        __builtin_amdgcn_s_sleep(1);
      }
      __builtin_amdgcn_sched_barrier(0);  // keep h loads behind the ballot
    }

    // Monolithic load+MFMA: 32 pipelined 16B loads (full K), 32 MFMAs,
    // 4 independent acc chains (depth 8) summed at the end.
    bf16x8 afr[32];
#pragma unroll
    for (int ki = 0; ki < 32; ++ki) afr[ki] = load_h16B(ab + ki * 32);

    f32x4 acc[4] = {};
#pragma unroll
    for (int ki = 0; ki < 32; ++ki)
      acc[ki & 3] = __builtin_amdgcn_mfma_f32_16x16x32_bf16(
          afr[ki], bfrag[ki], acc[ki & 3], 0, 0, 0);
    const f32x4 accs = (acc[0] + acc[1]) + (acc[2] + acc[3]);

    // Wave-local transpose (gate-major cols -> per-cell gates). Same wave
    // writes and reads: lgkmcnt(0) + sched_barrier, NO __syncthreads.
#pragma unroll
    for (int r = 0; r < 4; ++r) xpose[wave][fq * 4 + r][fm] = accs[r];
    asm volatile("s_waitcnt lgkmcnt(0)" ::: "memory");
    __builtin_amdgcn_sched_barrier(0);

    float gate[4];
#pragma unroll
    for (int g = 0; g < 4; ++g)
      gate[g] = xpose[wave][row_e][g * 4 + u_e] + xcur[g];

    const float ig = 1.f / (1.f + __expf(-gate[0]));
    const float fg = 1.f / (1.f + __expf(-gate[1]));
    const float gg = 1.f - 2.f / (__expf(2.f * gate[2]) + 1.f);  // tanh, inf-safe
    const float og = 1.f / (1.f + __expf(-gate[3]));
    c_reg = fg * c_reg + ig * gg;
    const float th = 1.f - 2.f / (__expf(2.f * c_reg) + 1.f);
    const float hv = og * th;

    // Device-coherent h store (write-through to LLC).
    __hip_atomic_store(&hn[(size_t)gb * HID + gj], f2bf(hv),
                       __ATOMIC_RELAXED, __HIP_MEMORY_SCOPE_AGENT);

    if (t == TSEQ - 1) {
      out[((size_t)gb * TSEQ + t) * HID + gj] = hv;
      out[(size_t)BATCH * TSEQ * HID + (size_t)gb * HID + gj] = hv;
      out[(size_t)BATCH * TSEQ * HID + (size_t)BATCH * HID + (size_t)gb * HID + gj] = c_reg;
      break;  // nobody consumes h(512); no flag needed
    }

    // Per-wave signal: drain THIS wave's h stores, bump the block counter;
    // the 4th wave of this step publishes the block flag. No barrier.
    asm volatile("s_waitcnt vmcnt(0)" ::: "memory");
    __builtin_amdgcn_sched_barrier(0);
    if (lane == 0) {
      const unsigned old = atomicAdd(&cnt, 1u);
      if (old == 4u * (unsigned)t + 3u)
        __hip_atomic_store(myflag, (unsigned)(t + 1),
                           __ATOMIC_RELAXED, __HIP_MEMORY_SCOPE_AGENT);
    }

    // out store AFTER the signal — off the producer->consumer critical path.
    out[((size_t)gb * TSEQ + t) * HID + gj] = hv;
  }
}

extern "C" void kernel_launch(void* const* d_in, const int* in_sizes, int n_in,
                              void* d_out, int out_size, void* d_ws, size_t ws_size,
                              hipStream_t stream) {
  (void)in_sizes; (void)n_in; (void)out_size;
  const float* x   = (const float*)d_in[0];
  const float* Wih = (const float*)d_in[1];
  const float* Whh = (const float*)d_in[2];
  const float* b   = (const float*)d_in[3];
  float* out = (float*)d_out;

  char* ws = (char*)d_ws;
  unsigned short* hbuf   = (unsigned short*)(ws + 1024);              // 256 KB
  unsigned short* x_bf   = (unsigned short*)(ws + 263168);            // 64 MB
  unsigned short* wih_bf = (unsigned short*)(ws + 263168 + 67108864); // 8 MB
  unsigned short* whh_bf = (unsigned short*)(ws + 263168 + 75497472); // 8 MB
  unsigned short* xg     = (unsigned short*)(ws + 263168 + 83886080); // 256 MB
  // Flags reuse the x_bf region (dead after gemm_xg): 4 groups x 64 x 128B.
  unsigned int* flags = (unsigned int*)x_bf;
  const size_t needed = 263168ULL + 83886080ULL + 268435456ULL;       // ~337 MB
  if (ws_size < needed) return;  // fail visibly (zero output)

  hipMemsetAsync(hbuf, 0, 2 * BATCH * HID * sizeof(unsigned short), stream);

  cvt_kernel<<<2048, 256, 0, stream>>>(x, x_bf, (MROWS * 1024) / 4);
  cvt_kernel<<<512, 256, 0, stream>>>(Wih, wih_bf, (NGATE * 1024) / 4);
  cvt_kernel<<<512, 256, 0, stream>>>(Whh, whh_bf, (NGATE * 1024) / 4);

  dim3 g(32, 256);  // (n-tiles, m-tiles)
  gemm_xg<<<g, 256, 0, stream>>>(x_bf, wih_bf, b, xg);

  // Zero progress flags AFTER gemm_xg (they live in the dead x_bf region).
  hipMemsetAsync(flags, 0, 4 * 64 * 128, stream);

  lstm_seq<<<256, 256, 0, stream>>>(whh_bf, xg, out, hbuf, flags);
}

// Round 7
// 2564.608 us; speedup vs baseline: 2.1429x; 2.1429x over previous
//
#include <hip/hip_runtime.h>
#include <stdint.h>

// LSTM: B=64, T=512, I=H=1024. bf16 MFMA path.
// Phase 1: Xg = x @ Wih^T + b  (m97-style 128x128 tile GEMM, permuted col layout)
// Phase 2: persistent 256-block kernel, 512 steps.
// R1: barrier rework — relaxed polling, Xg register prefetch.
// R2: zero cache-maintenance loop: h via agent-scope relaxed atomics.
// R3 (regressed): dataflow mask-loop — VALU-bound polling, MFMA serialization.
// R4: per-producer flags + 16-lane gather + __all ballot. 1724 us.
// R5 (regressed): tagged-h — poll mass scaled with data size, LLC congestion.
// R6 (regressed): 32-col blocks — doubled serial compute, stragglers weren't it.
// R7 (regressed): full-K per wave — 256-VGPR footprint spilled to scratch.
// R8: R4 base + three chain cuts:
//     (a) PER-WAVE flags (vmcnt is per-wave): each wave drains its own h
//         stores and signals its 4-row quarter; barrier #2 deleted. LDS
//         part[] protected by t-parity ping-pong; 2-step flag transitivity
//         closes the intra-block skew hazard.
//     (b) PACKED flags: 256 contiguous u32 per group -> consumer poll is one
//         fully-coalesced 64-lane gather over 4 lines (was 16 lines).
//     (c) tight poll (no s_sleep) -> detect ~1 LLC RT.

typedef __bf16 bf16x8 __attribute__((ext_vector_type(8)));
typedef float f32x4 __attribute__((ext_vector_type(4)));

#define BATCH 64
#define TSEQ 512
#define HID 1024
#define MROWS (BATCH * TSEQ)  // 32768
#define NGATE 4096

__device__ __forceinline__ unsigned short f2bf(float f) {
  union { float f; unsigned u; } v; v.f = f;
  unsigned r = (v.u + 0x7FFFu + ((v.u >> 16) & 1u)) >> 16;
  return (unsigned short)r;
}
__device__ __forceinline__ float bf2f(unsigned short u) {
  union { unsigned u; float f; } v; v.u = ((unsigned)u) << 16;
  return v.f;
}

__global__ void cvt_kernel(const float* __restrict__ src,
                           unsigned short* __restrict__ dst, int n4) {
  int i = blockIdx.x * blockDim.x + threadIdx.x;
  const int stride = gridDim.x * blockDim.x;
  for (; i < n4; i += stride) {
    float4 f = ((const float4*)src)[i];
    ushort4 u;
    u.x = f2bf(f.x); u.y = f2bf(f.y); u.z = f2bf(f.z); u.w = f2bf(f.w);
    ((ushort4*)dst)[i] = u;
  }
}

__device__ __forceinline__ void gl_lds16(const unsigned short* g, unsigned short* lds) {
  __builtin_amdgcn_global_load_lds(
      (const __attribute__((address_space(1))) unsigned int*)g,
      (__attribute__((address_space(3))) unsigned int*)lds, 16, 0, 0);
}

// ---------------- Phase 1 GEMM: Xg[r][perm(n)] = sum_k x[r][k]*Wih[n][k] + b[n]
// perm(n) = ((n&1023)>>4)*64 + (n>>10)*16 + (n&15): block bn of phase 2 reads
// 128B contiguous per row.
__global__ __launch_bounds__(256, 2) void gemm_xg(
    const unsigned short* __restrict__ A,   // x_bf   [32768][1024]
    const unsigned short* __restrict__ B,   // Wih_bf [4096][1024]
    const float* __restrict__ bias,         // [4096]
    unsigned short* __restrict__ Xg)        // [32768][4096] permuted cols
{
  __shared__ __align__(16) unsigned short Asm[128 * 32];  // 8 KB, swizzled
  __shared__ __align__(16) unsigned short Bsm[128 * 32];
  const int tid = threadIdx.x;
  const int lane = tid & 63;
  const int wave = tid >> 6;
  const int row0 = blockIdx.y * 128;
  const int col0 = blockIdx.x * 128;
  const int wm = (wave >> 1) * 64;
  const int wn = (wave & 1) * 64;
  const int s_ml = lane >> 2;
  const int s_q = ((lane & 3) ^ (s_ml >> 1)) & 3;
  const int fm = lane & 15;
  const int fq = lane >> 4;
  const int swz = ((fq ^ (fm >> 1)) & 3) * 8;

  f32x4 acc[4][4] = {};

  for (int kt = 0; kt < 32; ++kt) {
    const int k0 = kt * 32;
    __syncthreads();
#pragma unroll
    for (int gI = 0; gI < 2; ++gI) {
      const int grp = wave * 2 + gI;
      const unsigned short* ga =
          A + (size_t)(row0 + grp * 16 + s_ml) * 1024 + k0 + s_q * 8;
      gl_lds16(ga, &Asm[grp * 512]);
      const unsigned short* gb =
          B + (size_t)(col0 + grp * 16 + s_ml) * 1024 + k0 + s_q * 8;
      gl_lds16(gb, &Bsm[grp * 512]);
    }
    __syncthreads();
    bf16x8 af[4], bfv[4];
#pragma unroll
    for (int mt = 0; mt < 4; ++mt) {
      const int m = wm + mt * 16 + fm;
      af[mt] = *(const bf16x8*)&Asm[(m >> 4) * 512 + fm * 32 + swz];
    }
#pragma unroll
    for (int nt = 0; nt < 4; ++nt) {
      const int n = wn + nt * 16 + fm;
      bfv[nt] = *(const bf16x8*)&Bsm[(n >> 4) * 512 + fm * 32 + swz];
    }
#pragma unroll
    for (int mt = 0; mt < 4; ++mt)
#pragma unroll
      for (int nt = 0; nt < 4; ++nt)
        acc[mt][nt] = __builtin_amdgcn_mfma_f32_16x16x32_bf16(
            af[mt], bfv[nt], acc[mt][nt], 0, 0, 0);
  }
#pragma unroll
  for (int nt = 0; nt < 4; ++nt) {
    const int nb = col0 + wn + nt * 16;
    const int pbase = ((nb & 1023) >> 4) * 64 + (nb >> 10) * 16;
    const float bv = bias[nb + fm];
#pragma unroll
    for (int mt = 0; mt < 4; ++mt) {
#pragma unroll
      for (int r = 0; r < 4; ++r) {
        const int row = row0 + wm + mt * 16 + fq * 4 + r;
        Xg[(size_t)row * 4096 + pbase + fm] = f2bf(acc[mt][nt][r] + bv);
      }
    }
  }
}

// Device-coherent 16B h-fragment load: two 8B agent-scope relaxed atomic loads.
// Bypasses L1/L2 (device scope) so no ACQUIRE/buffer_inv is ever needed.
__device__ __forceinline__ bf16x8 load_h16B(const unsigned short* p) {
  union { unsigned long long q[2]; bf16x8 v; } u;
  const unsigned long long* q = (const unsigned long long*)p;
  u.q[0] = __hip_atomic_load(q, __ATOMIC_RELAXED, __HIP_MEMORY_SCOPE_AGENT);
  u.q[1] = __hip_atomic_load(q + 1, __ATOMIC_RELAXED, __HIP_MEMORY_SCOPE_AGENT);
  return u.v;
}

// ---------------- Phase 2: persistent recurrence, per-wave flag sync.
// 256 blocks: bn = blockIdx>>2 (hidden slice of 16), mi = blockIdx&3 (16 rows).
// Wave w holds Whh B-frags for its K-quarter in registers. c in registers.
// flags[mi][bn*4+wv] = t+1  <=>  wave wv of block (mi,bn) stored its 4-row
// quarter of h(t+1) (LLC-visible, own vmcnt drained) AND finished its step-t
// reads. Consumer wave w needs cols w*256..+256 = blocks w*16..+15, all 4
// waves each = flags[mi][w*64 .. w*64+63]: ONE coalesced 64-lane gather.
__global__ __launch_bounds__(256, 1) void lstm_seq(
    const unsigned short* __restrict__ Whh,  // [4096][1024] bf16
    const unsigned short* __restrict__ Xg,   // [32768][4096] bf16 permuted
    float* __restrict__ out,
    unsigned short* __restrict__ hbuf,       // 2 x [64][1024] bf16 ping-pong
    unsigned int* __restrict__ flags)        // [4 groups][256] u32 packed
{
  __shared__ float part[2][4][16][68];  // t-parity ping-pong, +4 pad
  const int tid = threadIdx.x;
  const int lane = tid & 63;
  const int wave = tid >> 6;
  const int bn = blockIdx.x >> 2;
  const int mi = blockIdx.x & 3;
  const int fm = lane & 15;
  const int fq = lane >> 4;
  unsigned int* flg = flags + mi * 256;       // group base, 1 KB
  unsigned int* myflag = flg + bn * 4 + wave; // this wave's flag
  unsigned int* pollp = flg + wave * 64 + lane;

  // Persistent B-frags: bfrag[gate][ki] = Whh[n][k], n=gate*1024+bn*16+fm,
  // k = wave*256 + ki*32 + fq*8 .. +8
  bf16x8 bfrag[4][8];
#pragma unroll
  for (int g = 0; g < 4; ++g) {
    const unsigned short* wrow =
        Whh + (size_t)(g * 1024 + bn * 16 + fm) * 1024 + wave * 256 + fq * 8;
#pragma unroll
    for (int ki = 0; ki < 8; ++ki) bfrag[g][ki] = *(const bf16x8*)(wrow + ki * 32);
  }

  const int em = tid >> 4, ej = tid & 15;   // elementwise: (batch-local, hidden-local)
  const int gb = mi * 16 + em;              // global batch row
  const int gj = bn * 16 + ej;              // global hidden index
  float c_reg = 0.f;

  unsigned short* h0 = hbuf;
  unsigned short* h1 = hbuf + BATCH * HID;

  // Prefetch Xg(0) into registers (read-once data, normal cached loads)
  const unsigned short* xrow = Xg + (size_t)gb * TSEQ * 4096 + bn * 64;
  float xpre[4];
#pragma unroll
  for (int g = 0; g < 4; ++g) xpre[g] = bf2f(xrow[g * 16 + ej]);

  for (int t = 0; t < TSEQ; ++t) {
    const unsigned short* hp = (t & 1) ? h1 : h0;
    unsigned short* hn = (t & 1) ? h0 : h1;
    const unsigned short* ab =
        hp + (size_t)(mi * 16 + fm) * 1024 + wave * 256 + fq * 8;

    // Rotate Xg regs; issue prefetch for t+1 early (hides under the poll)
    float xcur[4];
#pragma unroll
    for (int g = 0; g < 4; ++g) xcur[g] = xpre[g];
    if (t < TSEQ - 1) {
      const unsigned short* xn = xrow + (size_t)(t + 1) * 4096;
#pragma unroll
      for (int g = 0; g < 4; ++g) xpre[g] = bf2f(xn[g * 16 + ej]);
    }

    // Wave-level wait: all 64 wave-flags of this wave's 16 producer blocks
    // at >= t. One coalesced gather + one ballot per pass; tight spin.
    if (t > 0) {
      const unsigned tt = (unsigned)t;
      unsigned f = __hip_atomic_load(pollp, __ATOMIC_RELAXED,
                                     __HIP_MEMORY_SCOPE_AGENT);
      while (!__all((int)(f >= tt))) {
        f = __hip_atomic_load(pollp, __ATOMIC_RELAXED,
                              __HIP_MEMORY_SCOPE_AGENT);
      }
      __builtin_amdgcn_sched_barrier(0);  // keep h loads behind the ballot
    }

    // Monolithic load+MFMA block (8 pipelined 16B loads vs 32 MFMAs).
    bf16x8 afr[8];
#pragma unroll
    for (int ki = 0; ki < 8; ++ki) afr[ki] = load_h16B(ab + ki * 32);

    f32x4 acc[4] = {};
#pragma unroll
    for (int ki = 0; ki < 8; ++ki)
#pragma unroll
      for (int g = 0; g < 4; ++g)
        acc[g] = __builtin_amdgcn_mfma_f32_16x16x32_bf16(afr[ki], bfrag[g][ki],
                                                         acc[g], 0, 0, 0);

    float (*pp)[16][68] = part[t & 1];
#pragma unroll
    for (int g = 0; g < 4; ++g)
#pragma unroll
      for (int r = 0; r < 4; ++r)
        pp[wave][fq * 4 + r][g * 16 + fm] = acc[g][r];
    // Single barrier per step: joins the 4 waves for the K-reduce. Union of
    // their polls covers all 64 blocks x 4 waves >= t => overwriting h(t-1)
    // below is safe. part[] reuse protected by t-parity + 2-step flag
    // transitivity (flags >= t+2 imply every wave finished step t+1).
    __syncthreads();

    // K-reduce over 4 waves + Xg + elementwise (1 (b,j) cell per thread)
    float gate[4];
#pragma unroll
    for (int g = 0; g < 4; ++g) {
      float s = pp[0][em][g * 16 + ej] + pp[1][em][g * 16 + ej] +
                pp[2][em][g * 16 + ej] + pp[3][em][g * 16 + ej];
      gate[g] = s + xcur[g];
    }
    const float ig = 1.f / (1.f + __expf(-gate[0]));
    const float fg = 1.f / (1.f + __expf(-gate[1]));
    const float gg = 1.f - 2.f / (__expf(2.f * gate[2]) + 1.f);  // tanh, inf-safe
    const float og = 1.f / (1.f + __expf(-gate[3]));
    c_reg = fg * c_reg + ig * gg;
    const float th = 1.f - 2.f / (__expf(2.f * c_reg) + 1.f);
    const float hv = og * th;

    // Device-coherent h store (write-through to LLC).
    __hip_atomic_store(&hn[(size_t)gb * HID + gj], f2bf(hv),
                       __ATOMIC_RELAXED, __HIP_MEMORY_SCOPE_AGENT);

    if (t == TSEQ - 1) {
      out[((size_t)gb * TSEQ + t) * HID + gj] = hv;
      out[(size_t)BATCH * TSEQ * HID + (size_t)gb * HID + gj] = hv;
      out[(size_t)BATCH * TSEQ * HID + (size_t)BATCH * HID + (size_t)gb * HID + gj] = c_reg;
      break;  // nobody consumes h(512); no flag needed
    }

    // Per-wave signal: vmcnt is a WAVE-level counter, so this drain covers
    // all 64 lanes' h stores. No cross-wave join needed before signaling.
    asm volatile("s_waitcnt vmcnt(0)" ::: "memory");
    __builtin_amdgcn_sched_barrier(0);
    if (lane == 0)
      __hip_atomic_store(myflag, (unsigned)(t + 1),
                         __ATOMIC_RELAXED, __HIP_MEMORY_SCOPE_AGENT);

    // out store AFTER the signal — off the producer->consumer critical path
    // (and outside the drained window, so the HBM write ack is never waited).
    out[((size_t)gb * TSEQ + t) * HID + gj] = hv;
  }
}

extern "C" void kernel_launch(void* const* d_in, const int* in_sizes, int n_in,
                              void* d_out, int out_size, void* d_ws, size_t ws_size,
                              hipStream_t stream) {
  (void)in_sizes; (void)n_in; (void)out_size;
  const float* x   = (const float*)d_in[0];
  const float* Wih = (const float*)d_in[1];
  const float* Whh = (const float*)d_in[2];
  const float* b   = (const float*)d_in[3];
  float* out = (float*)d_out;

  char* ws = (char*)d_ws;
  unsigned short* hbuf   = (unsigned short*)(ws + 1024);              // 256 KB
  unsigned short* x_bf   = (unsigned short*)(ws + 263168);            // 64 MB
  unsigned short* wih_bf = (unsigned short*)(ws + 263168 + 67108864); // 8 MB
  unsigned short* whh_bf = (unsigned short*)(ws + 263168 + 75497472); // 8 MB
  unsigned short* xg     = (unsigned short*)(ws + 263168 + 83886080); // 256 MB
  // Flags reuse the x_bf region (dead after gemm_xg): 4 groups x 1 KB packed.
  unsigned int* flags = (unsigned int*)x_bf;
  const size_t needed = 263168ULL + 83886080ULL + 268435456ULL;       // ~337 MB
  if (ws_size < needed) return;  // fail visibly (zero output)

  hipMemsetAsync(hbuf, 0, 2 * BATCH * HID * sizeof(unsigned short), stream);

  cvt_kernel<<<2048, 256, 0, stream>>>(x, x_bf, (MROWS * 1024) / 4);
  cvt_kernel<<<512, 256, 0, stream>>>(Wih, wih_bf, (NGATE * 1024) / 4);
  cvt_kernel<<<512, 256, 0, stream>>>(Whh, whh_bf, (NGATE * 1024) / 4);

  dim3 g(32, 256);  // (n-tiles, m-tiles)
  gemm_xg<<<g, 256, 0, stream>>>(x_bf, wih_bf, b, xg);

  // Zero progress flags AFTER gemm_xg (they live in the dead x_bf region).
  hipMemsetAsync(flags, 0, 4 * 256 * sizeof(unsigned int), stream);

  lstm_seq<<<256, 256, 0, stream>>>(whh_bf, xg, out, hbuf, flags);
}